// Round 7
// baseline (157.450 us; speedup 1.0000x reference)
//
#include <hip/hip_runtime.h>

#define EDGES   262144
#define CTPB    256
#define SCHUNK  256
#define NINT    2048               // 32 rblocks * 8 schunks * 8 segments
#define EPB     (EDGES / NINT)     // 128 edges folded into each block
#define NODESB  4096
#define PPB     (NODESB / NINT)    // 2 prior nodes per block

typedef float v2f __attribute__((ext_vector_type(2)));

// SS = sqrt(log2(e)). Staged integral coords pre-scaled by SS: exp argument
// lands in log2 domain (raw v_exp_f32, no x1.4427 mul) and the erf-arg scale
// folds into rescaled poly coefficients + the final constant.
#define SS 1.2011224087864498f

__device__ __forceinline__ float fast_rsq(float x) { return __builtin_amdgcn_rsqf(x); }
__device__ __forceinline__ float fast_ex2(float x) {
    float r; asm("v_exp_f32 %0, %1" : "=v"(r) : "v"(x)); return r;
}

// Odd degree-9 poly for erf, argument pre-scaled by SS (y = SS*x -> erf(x)).
// Coeffs = round-0 coeffs / SS^(2k+1); clamp at 2*SS (erf(2)=0.9953).
__device__ __forceinline__ v2f erf_poly2(v2f x) {
    v2f c;
    c.x = __builtin_amdgcn_fmed3f(x.x, -2.4022448f, 2.4022448f);
    c.y = __builtin_amdgcn_fmed3f(x.y, -2.4022448f, 2.4022448f);
    v2f t = c * c;
    v2f p = t * 2.30540e-4f - 4.58723e-3f;
    p = p * t + 0.0400696f;
    p = p * t - 0.2136547f;
    p = p * t + 0.9390508f;
    return c * p;
}

template <int NW>
__device__ __forceinline__ float block_reduce(float v, float* sm) {
    #pragma unroll
    for (int o = 32; o > 0; o >>= 1) v += __shfl_down(v, o, 64);
    int lane = threadIdx.x & 63;
    int wid  = threadIdx.x >> 6;
    if (lane == 0) sm[wid] = v;
    __syncthreads();
    float r = 0.0f;
    if (threadIdx.x == 0) {
        #pragma unroll
        for (int w = 0; w < NW; ++w) r += sm[w];
    }
    return r;
}

// 2048 uniform blocks. Each: one integral tile (256 senders x 256 receivers,
// R6-identical inner loop) + 128 edges + 2 prior nodes folded in.
// Edge/prior INDEX loads are issued at kernel top (latency hidden under
// staging+loop); the dependent Z gathers run post-loop (L2-resident, ~0.5us).
// Block partial = Kc*Q + sum|w|^2 + 10*P (pre-combined; linear).
// mode=1: part[bid]; mode=0: atomicAdd into part[0].
__global__ __launch_bounds__(CTPB) void k_mega(const float* __restrict__ Z,
        const float* __restrict__ ts, const int* __restrict__ snd,
        const int* __restrict__ rcv, const int* __restrict__ nodes,
        const int* __restrict__ su, const float* __restrict__ cp,
        const float* __restrict__ betap, float* __restrict__ part, int mode) {
    __shared__ __align__(16) float sZx[SCHUNK];
    __shared__ __align__(16) float sZy[SCHUNK];
    __shared__ __align__(16) float sDx[SCHUNK];
    __shared__ __align__(16) float sDy[SCHUNK];
    __shared__ float smr[CTPB / 64];
    const int bid = blockIdx.x;
    const int tid = threadIdx.x;
    const int k  = bid >> 8;
    const int sc = (bid >> 5) & 7;
    const int rb = bid & 31;

    // ---- prefetch edge / prior indices (coalesced; consumed post-loop) ----
    float e_ts = 0.0f; int e_s = 0, e_r = 0, p_n = 0;
    if (tid < EPB) {
        int e = bid * EPB + tid;
        e_ts = ts[e]; e_s = snd[e]; e_r = rcv[e];
    } else if (tid < EPB + PPB) {
        p_n = nodes[bid * PPB + (tid - EPB)];
    }
    const float seg = cp[1] - cp[0];

    // ---- staging: identical to R6 ----
    {
        int n = su[sc * SCHUNK + tid];
        const float* z = Z + n * 18 + k;
        float zx = z[0] * SS, zy = z[9] * SS;
        sZx[tid] = zx; sZy[tid] = zy;
        sDx[tid] = z[1] * SS - zx; sDy[tid] = z[10] * SS - zy;
    }
    const float* zr = Z + (rb * CTPB + tid) * 18 + k;
    float rzx = zr[0] * SS, rzy = zr[9] * SS;
    float rdx = zr[1] * SS - rzx, rdy = zr[10] * SS - rzy;
    __syncthreads();

    // ---- main loop: identical to R6 ----
    const v2f* pZx = (const v2f*)sZx;
    const v2f* pZy = (const v2f*)sZy;
    const v2f* pDx = (const v2f*)sDx;
    const v2f* pDy = (const v2f*)sDy;
    float s0 = 0.0f, s1 = 0.0f;
    #pragma unroll 4
    for (int i = 0; i < SCHUNK / 2; ++i) {
        v2f wx = pZx[i] - rzx;
        v2f wy = pZy[i] - rzy;
        v2f vx = pDx[i] - rdx;
        v2f vy = pDy[i] - rdy;
        v2f D  = wx * wx + wy * wy;
        v2f S  = vx * vx + vy * vy;
        v2f mc = vx * wx + vy * wy;          // = -C (scaled)
        // rs clamped so the S==0 diagonal needs no mask: mc==0 exactly there,
        // so m=0*1e18=0 (not NaN), rt=0, ea=-0, ex=1, e=P(0)+P(-0)=0.
        // |u|<=sqrt(D) (Cauchy-Schwarz) bounds ea<=0: exp never overflows.
        v2f rsq;
        rsq.x = fminf(fast_rsq(S.x), 1e18f);
        rsq.y = fminf(fast_rsq(S.y), 1e18f);
        v2f u  = -mc * rsq;                  // C * rsq (scaled)
        v2f rt = S * rsq;                    // sqrt(S) (scaled)
        v2f ea = u * u - D;                  // log2-domain exp arg
        v2f ex;
        ex.x = fast_ex2(ea.x);
        ex.y = fast_ex2(ea.y);
        v2f e  = erf_poly2(rt - u) + erf_poly2(u);
        v2f re = rsq * e;
        s0 = fmaf(ex.x, re.x, s0);
        s1 = fmaf(ex.y, re.y, s1);
    }

    // ---- post-loop tail: edge-Z gather + prior (indices already in regs) ----
    float extra = 0.0f;
    if (tid < EPB) {
        float x  = e_ts / seg;
        float kf = floorf(x);
        int kap  = (int)kf;
        float d  = x - kf, od = 1.0f - d;
        const float* zs = Z + e_s * 18 + kap;
        const float* zq = Z + e_r * 18 + kap;
        float ux = zs[0] - zq[0],  uy = zs[9]  - zq[9];
        float vx = zs[1] - zq[1],  vy = zs[10] - zq[10];
        float wx = fmaf(od, ux, d * vx);
        float wy = fmaf(od, uy, d * vy);
        extra = fmaf(wx, wx, wy * wy);       // -flt_e contributes +|w|^2
    } else if (tid < EPB + PPB) {
        const float* z = Z + p_n * 18;
        float s = 0.0f;
        #pragma unroll
        for (int dd = 0; dd < 2; ++dd) {
            float prev = z[dd * 9];
            s = fmaf(prev, prev, s);
            #pragma unroll
            for (int kk = 1; kk <= 8; ++kk) {
                float cur = z[dd * 9 + kk];
                float df  = cur - prev;
                s = fmaf(df, df, s);
                prev = cur;
            }
        }
        extra = 10.0f * s;
    }

    // Kc = sqrt2pi * 0.5(scan) * 0.5(erf pair) * sqrt(0.5)(sigma) * SS * seg
    //    * exp(beta) = 0.53223360 * seg * exp(beta)
    const float Kc = 0.53223360f * seg * __expf(betap[0]);
    float v = fmaf(Kc, s0 + s1, extra);
    float r = block_reduce<CTPB / 64>(v, smr);
    if (tid == 0) {
        if (mode) part[bid] = r;
        else      atomicAdd(part, r);
    }
}

__global__ __launch_bounds__(CTPB) void k_final(const float* __restrict__ ws,
        int mode, const float* __restrict__ betap, const int* __restrict__ fsp,
        float* __restrict__ out, float n_entries, float bs) {
    __shared__ float sm[CTPB / 64];
    int tid = threadIdx.x;
    float a = 0.0f;
    if (mode) {
        for (int i = tid; i < NINT; i += CTPB) a += ws[i];
        a = block_reduce<CTPB / 64>(a, sm);
    } else if (tid == 0) {
        a = ws[0];
    }
    if (tid == 0) {
        float res = a - betap[0] * n_entries;
        out[0] = ((float)fsp[0] / bs) * res;
    }
}

extern "C" void kernel_launch(void* const* d_in, const int* in_sizes, int n_in,
                              void* d_out, int out_size, void* d_ws, size_t ws_size,
                              hipStream_t stream) {
    const float* Z    = (const float*)d_in[0];
    const float* beta = (const float*)d_in[1];
    const float* ts   = (const float*)d_in[2];
    const int*   snd  = (const int*)d_in[3];
    const int*   rcv  = (const int*)d_in[4];
    const int*   nodes= (const int*)d_in[5];
    const int*   su   = (const int*)d_in[6];
    const float* cp   = (const float*)d_in[7];
    const int*   fs   = (const int*)d_in[8];
    float* acc = (float*)d_ws;

    const int mode = (ws_size >= NINT * sizeof(float)) ? 1 : 0;
    if (!mode) hipMemsetAsync(acc, 0, sizeof(float), stream);
    k_mega<<<NINT, CTPB, 0, stream>>>(Z, ts, snd, rcv, nodes, su, cp, beta,
                                      acc, mode);
    k_final<<<1, CTPB, 0, stream>>>(acc, mode, beta, fs, (float*)d_out,
                                    (float)in_sizes[2], (float)in_sizes[5]);
}

// Round 8
// 155.318 us; speedup vs baseline: 1.0137x; 1.0137x over previous
//
#include <hip/hip_runtime.h>

#define EDGES   262144
#define CTPB    256
#define SCHUNK  256
#define NINT    2048   // 32 rblocks * 8 schunks * 8 segments
#define NFLT    (EDGES / CTPB)   // 1024
#define NPRI    16     // 4096 nodes / 256
#define NBLK    (NINT + NFLT + NPRI)

typedef float v2f __attribute__((ext_vector_type(2)));

// SS = sqrt(log2(e)). Staged integral coords pre-scaled by SS: exp argument
// lands in log2 domain (raw v_exp_f32, no x1.4427 mul) and the erf-arg scale
// folds into rescaled poly coefficients + the final constant (x SS in k_final).
#define SS 1.2011224087864498f

__device__ __forceinline__ float fast_rsq(float x) { return __builtin_amdgcn_rsqf(x); }
__device__ __forceinline__ float fast_ex2(float x) {
    float r; asm("v_exp_f32 %0, %1" : "=v"(r) : "v"(x)); return r;
}

// Odd degree-9 poly for erf, argument pre-scaled by SS (y = SS*x -> erf(x)).
// Coeffs = round-0 coeffs / SS^(2k+1); clamp at 2*SS (erf(2)=0.9953).
__device__ __forceinline__ v2f erf_poly2(v2f x) {
    v2f c;
    c.x = __builtin_amdgcn_fmed3f(x.x, -2.4022448f, 2.4022448f);
    c.y = __builtin_amdgcn_fmed3f(x.y, -2.4022448f, 2.4022448f);
    v2f t = c * c;
    v2f p = t * 2.30540e-4f - 4.58723e-3f;
    p = p * t + 0.0400696f;
    p = p * t - 0.2136547f;
    p = p * t + 0.9390508f;
    return c * p;
}

template <int NW>
__device__ __forceinline__ float block_reduce(float v, float* sm) {
    #pragma unroll
    for (int o = 32; o > 0; o >>= 1) v += __shfl_down(v, o, 64);
    int lane = threadIdx.x & 63;
    int wid  = threadIdx.x >> 6;
    if (lane == 0) sm[wid] = v;
    __syncthreads();
    float r = 0.0f;
    if (threadIdx.x == 0) {
        #pragma unroll
        for (int w = 0; w < NW; ++w) r += sm[w];
    }
    return r;
}

// Blocks [0,NINT): integral; [NINT,NINT+NFLT): edge term; rest: prior.
// mode=1: write block partial to part[bid]; mode=0: atomicAdd into part[0..2].
__global__ __launch_bounds__(CTPB) void k_mega(const float* __restrict__ Z,
        const float* __restrict__ ts, const int* __restrict__ snd,
        const int* __restrict__ rcv, const int* __restrict__ nodes,
        const int* __restrict__ su, const float* __restrict__ cp,
        float* __restrict__ part, int mode) {
    __shared__ __align__(16) float sZx[SCHUNK];
    __shared__ __align__(16) float sZy[SCHUNK];
    __shared__ __align__(16) float sDx[SCHUNK];
    __shared__ __align__(16) float sDy[SCHUNK];
    __shared__ float smr[CTPB / 64];
    const int bid = blockIdx.x;
    const int tid = threadIdx.x;
    float r;
    int slot;

    if (bid < NINT) {
        // ---- integral over sender-chunk x receiver-block pairs ----
        // D=|w|^2, S=|v|^2, C=-<v,w> with w=Zs0-Zr0, v=DZs-DZr (all x SS)
        const int k  = bid >> 8;
        const int sc = (bid >> 5) & 7;
        const int rb = bid & 31;
        {
            int n = su[sc * SCHUNK + tid];
            const float* z = Z + n * 18 + k;
            float zx = z[0] * SS, zy = z[9] * SS;
            sZx[tid] = zx; sZy[tid] = zy;
            sDx[tid] = z[1] * SS - zx; sDy[tid] = z[10] * SS - zy;
        }
        const float* zr = Z + (rb * CTPB + tid) * 18 + k;
        float rzx = zr[0] * SS, rzy = zr[9] * SS;
        float rdx = zr[1] * SS - rzx, rdy = zr[10] * SS - rzy;
        __syncthreads();

        const v2f* pZx = (const v2f*)sZx;
        const v2f* pZy = (const v2f*)sZy;
        const v2f* pDx = (const v2f*)sDx;
        const v2f* pDy = (const v2f*)sDy;
        float s0 = 0.0f, s1 = 0.0f;
        #pragma unroll 4
        for (int i = 0; i < SCHUNK / 2; ++i) {
            v2f wx = pZx[i] - rzx;
            v2f wy = pZy[i] - rzy;
            v2f vx = pDx[i] - rdx;
            v2f vy = pDy[i] - rdy;
            v2f D  = wx * wx + wy * wy;
            v2f S  = vx * vx + vy * vy;
            v2f mc = vx * wx + vy * wy;          // = -C (scaled)
            // rs clamped so the S==0 diagonal needs no mask: mc==0 exactly
            // there, so m=0*1e18=0 (not 0*inf=NaN), rt=0, ea=-D=-0, ex=1,
            // e=P(0)+P(-0)=0 -> contribution exactly 0. Off-diagonal rsq
            // is ~<=1e6, far below the clamp. |u|<=sqrt(D) (Cauchy-Schwarz)
            // bounds ea<=0, so exp never overflows either.
            v2f rsq;
            rsq.x = fminf(fast_rsq(S.x), 1e18f);
            rsq.y = fminf(fast_rsq(S.y), 1e18f);
            v2f u  = -mc * rsq;                  // C * rsq (scaled)
            v2f rt = S * rsq;                    // sqrt(S) (scaled)
            v2f ea = u * u - D;                  // log2-domain exp arg
            v2f ex;
            ex.x = fast_ex2(ea.x);
            ex.y = fast_ex2(ea.y);
            v2f e  = erf_poly2(rt - u) + erf_poly2(u);
            v2f re = rsq * e;
            s0 = fmaf(ex.x, re.x, s0);
            s1 = fmaf(ex.y, re.y, s1);
        }
        r = block_reduce<CTPB / 64>(s0 + s1, smr);
        slot = 2;
    } else if (bid < NINT + NFLT) {
        // ---- edge likelihood: -|od*(Zs_c-Zr_c) + d*(Zs_n-Zr_n)|^2 ----
        int e = (bid - NINT) * CTPB + tid;
        float seg = cp[1] - cp[0];
        float x   = ts[e] / seg;
        float kf  = floorf(x);
        int kappa = (int)kf;
        float d   = x - kf;
        float od  = 1.0f - d;
        int sb = snd[e] * 18, rbse = rcv[e] * 18;
        float ux = Z[sb + kappa]     - Z[rbse + kappa];
        float uy = Z[sb + 9 + kappa] - Z[rbse + 9 + kappa];
        float vx = Z[sb + kappa + 1]     - Z[rbse + kappa + 1];
        float vy = Z[sb + 9 + kappa + 1] - Z[rbse + 9 + kappa + 1];
        float wx = od * ux + d * vx;
        float wy = od * uy + d * vy;
        r = block_reduce<CTPB / 64>(-fmaf(wx, wx, wy * wy), smr);
        slot = 1;
    } else {
        // ---- prior ----
        int i = (bid - NINT - NFLT) * CTPB + tid;
        int n = nodes[i];
        const float* z = Z + n * 18;
        float s = 0.0f;
        #pragma unroll
        for (int d = 0; d < 2; ++d) {
            float prev = z[d * 9];
            s = fmaf(prev, prev, s);
            #pragma unroll
            for (int k = 1; k <= 8; ++k) {
                float cur = z[d * 9 + k];
                float df  = cur - prev;
                s = fmaf(df, df, s);
                prev = cur;
            }
        }
        r = block_reduce<CTPB / 64>(s, smr);
        slot = 0;
    }
    if (tid == 0) {
        if (mode) part[bid] = r;
        else      atomicAdd(part + slot, r);
    }
}

__global__ __launch_bounds__(CTPB) void k_final(const float* __restrict__ ws,
        int mode, const float* __restrict__ betap, const int* __restrict__ fsp,
        const float* __restrict__ cp, float* __restrict__ out,
        float n_entries, float bs) {
    __shared__ float sm0[CTPB / 64], sm1[CTPB / 64], sm2[CTPB / 64];
    int tid = threadIdx.x;
    float pr, fl, qq;
    if (mode) {
        float q = 0.0f, f = 0.0f, p = 0.0f;
        for (int i = tid; i < NBLK; i += CTPB) {
            float v = ws[i];
            if (i < NINT)             q += v;
            else if (i < NINT + NFLT) f += v;
            else                      p += v;
        }
        qq = block_reduce<CTPB / 64>(q, sm0);
        fl = block_reduce<CTPB / 64>(f, sm1);
        pr = block_reduce<CTPB / 64>(p, sm2);
    } else {
        pr = ws[0]; fl = ws[1]; qq = ws[2];
    }
    if (tid == 0) {
        float prior  = 10.0f * pr;
        float beta   = betap[0];
        float fs     = (float)fsp[0];
        float seg    = cp[1] - cp[0];
        // integral = 0.5(scan) * 0.5(erf pair) * sqrt(0.5)(sigma) * SS * dt * Q
        //   (extra SS factor compensates the q/SS from scaled rsq)
        float integral = 0.21233045f * seg * qq;
        const float sqrt2pi = 2.5066282746310002f;
        float res = prior - beta * n_entries - fl + sqrt2pi * expf(beta) * integral;
        out[0] = (fs / bs) * res;
    }
}

extern "C" void kernel_launch(void* const* d_in, const int* in_sizes, int n_in,
                              void* d_out, int out_size, void* d_ws, size_t ws_size,
                              hipStream_t stream) {
    const float* Z    = (const float*)d_in[0];
    const float* beta = (const float*)d_in[1];
    const float* ts   = (const float*)d_in[2];
    const int*   snd  = (const int*)d_in[3];
    const int*   rcv  = (const int*)d_in[4];
    const int*   nodes= (const int*)d_in[5];
    const int*   su   = (const int*)d_in[6];
    const float* cp   = (const float*)d_in[7];
    const int*   fs   = (const int*)d_in[8];
    float* acc = (float*)d_ws;

    const int mode = (ws_size >= NBLK * sizeof(float)) ? 1 : 0;
    if (!mode) hipMemsetAsync(acc, 0, 3 * sizeof(float), stream);
    k_mega<<<NBLK, CTPB, 0, stream>>>(Z, ts, snd, rcv, nodes, su, cp, acc, mode);
    k_final<<<1, CTPB, 0, stream>>>(acc, mode, beta, fs, cp, (float*)d_out,
                                    (float)in_sizes[2], (float)in_sizes[5]);
}